// Round 1
// baseline (2235.284 us; speedup 1.0000x reference)
//
#include <hip/hip_runtime.h>
#include <hip/hip_bf16.h>

#define TT   2048
#define BB   512
#define IN_  27
#define HH   64
#define NG   256   // 4*H
#define OUTD 26
#define EPSV 1e-5f

__device__ __forceinline__ float bcastf(float v, int lane) {
    return __int_as_float(__builtin_amdgcn_readlane(__float_as_int(v), lane));
}

__device__ __forceinline__ float sigm(float x) {
    return 1.0f / (1.0f + __expf(-x));
}

__device__ __forceinline__ float tanh_fast(float x) {
    float e = __expf(-2.0f * fabsf(x));
    float r = (1.0f - e) / (1.0f + e);
    return copysignf(r, x);
}

// Phase 1: sequential LSTM over tc timesteps. One block per batch element.
// threadIdx.x = gate index j (0..255). q = j>>6 selects i/f/g/o (wave-uniform).
// Lane l of every wave holds h[l], c[l] (replicated across the 4 waves so the
// cell update needs no second barrier and no LDS round-trip for h).
__global__ __launch_bounds__(256, 2) void lstm_seq(
    const float* __restrict__ x,     // [T,B,IN]
    const float* __restrict__ W_ih,  // [NG,IN]
    const float* __restrict__ W_hh,  // [NG,H]
    const float* __restrict__ b_ih,  // [NG]
    const float* __restrict__ b_hh,  // [NG]
    float* __restrict__ h_all,       // [tc,B,H] (workspace)
    float* __restrict__ state,       // [2,B,H]  (workspace: h then c)
    int t0, int tc, int first)
{
    const int b = blockIdx.x;
    const int j = threadIdx.x;   // gate index
    const int q = j >> 6;        // 0=i 1=f 2=g 3=o (uniform per wave)
    const int l = j & 63;        // lane / h-index

    // Weights register-resident: 27 + 64 = 91 VGPRs per lane.
    float wi[IN_];
#pragma unroll
    for (int k = 0; k < IN_; ++k) wi[k] = W_ih[j * IN_ + k];
    float wh[HH];
#pragma unroll
    for (int k = 0; k < HH; ++k) wh[k] = W_hh[j * HH + k];
    const float bias = b_ih[j] + b_hh[j];

    float hv, cv;
    if (first) {
        hv = 0.0f; cv = 0.0f;
    } else {
        hv = state[b * HH + l];
        cv = state[BB * HH + b * HH + l];
    }

    __shared__ float acts[2][NG];  // double-buffered -> one barrier per step

    for (int tl = 0; tl < tc; ++tl) {
        const int t = t0 + tl;

        // x_t[b, l] into lanes 0..26 (in flight while h-dot issues)
        float xv = 0.0f;
        if (l < IN_) xv = x[((size_t)t * BB + b) * IN_ + l];

        // gate_j = bias + sum_k W_hh[j,k] h[k] + sum_k W_ih[j,k] x[k]
        // 4 accumulators for ILP (break the fmac dependency chain).
        float a0 = bias, a1 = 0.0f, a2 = 0.0f, a3 = 0.0f;
#pragma unroll
        for (int k = 0; k < HH; k += 4) {
            a0 = fmaf(bcastf(hv, k + 0), wh[k + 0], a0);
            a1 = fmaf(bcastf(hv, k + 1), wh[k + 1], a1);
            a2 = fmaf(bcastf(hv, k + 2), wh[k + 2], a2);
            a3 = fmaf(bcastf(hv, k + 3), wh[k + 3], a3);
        }
#pragma unroll
        for (int k = 0; k < 24; k += 4) {
            a0 = fmaf(bcastf(xv, k + 0), wi[k + 0], a0);
            a1 = fmaf(bcastf(xv, k + 1), wi[k + 1], a1);
            a2 = fmaf(bcastf(xv, k + 2), wi[k + 2], a2);
            a3 = fmaf(bcastf(xv, k + 3), wi[k + 3], a3);
        }
        a0 = fmaf(bcastf(xv, 24), wi[24], a0);
        a1 = fmaf(bcastf(xv, 25), wi[25], a1);
        a2 = fmaf(bcastf(xv, 26), wi[26], a2);
        const float acc = (a0 + a1) + (a2 + a3);

        // activation (branch is wave-uniform: q==2 is the g wave)
        const float av = (q == 2) ? tanh_fast(acc) : sigm(acc);

        acts[tl & 1][j] = av;
        __syncthreads();

        const float gi = acts[tl & 1][l];
        const float gf = acts[tl & 1][HH + l];
        const float gg = acts[tl & 1][2 * HH + l];
        const float go = acts[tl & 1][3 * HH + l];

        const float cn = fmaf(gf, cv, gi * gg);
        const float hn = go * tanh_fast(cn);
        cv = cn;
        hv = hn;

        if (q == 0) h_all[((size_t)tl * BB + b) * HH + l] = hn;
        // no second barrier: next step writes the OTHER acts buffer, and
        // re-writing this buffer happens only after the next barrier.
    }

    if (q == 0) {
        state[b * HH + l] = hv;
        state[BB * HH + b * HH + l] = cv;
    }
}

// Phase 2: per-timestep BatchNorm (batch stats) + locked dropout + maxpool
// over batch + FC. One block per timestep, fully parallel over tc.
__global__ __launch_bounds__(256, 2) void bn_pool_fc(
    const float* __restrict__ h_all,  // [tc,B,H]
    const float* __restrict__ gamma,  // [H]
    const float* __restrict__ beta,   // [H]
    const float* __restrict__ dmask,  // [B,H]
    const float* __restrict__ pg,     // [T,OUT]
    const float* __restrict__ W_fc,   // [OUT, H+OUT]
    const float* __restrict__ b_fc,   // [OUT]
    float* __restrict__ y,            // [T,OUT]
    int t0, int tc)
{
    const int tl = blockIdx.x;
    const int t = t0 + tl;
    const int tid = threadIdx.x;
    const int g = tid >> 6;      // 4 batch groups
    const int hcol = tid & 63;
    const float* hp = h_all + (size_t)tl * BB * HH;

    __shared__ float s_a[4][HH];
    __shared__ float s_b[4][HH];
    __shared__ float s_scale[HH];
    __shared__ float s_shift[HH];
    __shared__ float s_pool[HH];

    // pass 1: sum and sumsq over batch (coalesced: lane = hcol)
    float sum = 0.0f, sq = 0.0f;
    for (int bb = g; bb < BB; bb += 4) {
        const float v = hp[bb * HH + hcol];
        sum += v;
        sq = fmaf(v, v, sq);
    }
    s_a[g][hcol] = sum;
    s_b[g][hcol] = sq;
    __syncthreads();

    if (tid < HH) {
        const float s  = (s_a[0][tid] + s_a[1][tid]) + (s_a[2][tid] + s_a[3][tid]);
        const float q2 = (s_b[0][tid] + s_b[1][tid]) + (s_b[2][tid] + s_b[3][tid]);
        const float mean = s * (1.0f / BB);
        const float var  = q2 * (1.0f / BB) - mean * mean;  // biased var
        const float rs = rsqrtf(var + EPSV);
        const float sc = rs * gamma[tid];
        s_scale[tid] = sc;
        s_shift[tid] = beta[tid] - mean * sc;
    }
    __syncthreads();

    // pass 2: normalize + locked dropout + max over batch
    const float sc = s_scale[hcol];
    const float sh = s_shift[hcol];
    float m = -3.0e38f;
    for (int bb = g; bb < BB; bb += 4) {
        const float v = hp[bb * HH + hcol];
        const float hd = fmaf(v, sc, sh) * dmask[bb * HH + hcol];
        m = fmaxf(m, hd);
    }
    s_a[g][hcol] = m;
    __syncthreads();
    if (tid < HH) {
        s_pool[tid] = fmaxf(fmaxf(s_a[0][tid], s_a[1][tid]),
                            fmaxf(s_a[2][tid], s_a[3][tid]));
    }
    __syncthreads();

    // FC: y[t, o] = b_fc[o] + W_fc[o, 0:64].pool + W_fc[o, 64:90].pg[t]
    if (tid < OUTD) {
        float acc = b_fc[tid];
        const float* w = W_fc + tid * (HH + OUTD);
#pragma unroll
        for (int k = 0; k < HH; ++k) acc = fmaf(w[k], s_pool[k], acc);
#pragma unroll
        for (int k = 0; k < OUTD; ++k) acc = fmaf(w[HH + k], pg[t * OUTD + k], acc);
        y[t * OUTD + tid] = acc;
    }
}

extern "C" void kernel_launch(void* const* d_in, const int* in_sizes, int n_in,
                              void* d_out, int out_size, void* d_ws, size_t ws_size,
                              hipStream_t stream)
{
    const float* x     = (const float*)d_in[0];   // [T,B,IN]
    const float* pg    = (const float*)d_in[1];   // [T,OUT]
    const float* W_ih  = (const float*)d_in[2];   // [4H,IN]
    const float* W_hh  = (const float*)d_in[3];   // [4H,H]
    const float* b_ih  = (const float*)d_in[4];
    const float* b_hh  = (const float*)d_in[5];
    const float* gamma = (const float*)d_in[6];
    const float* beta  = (const float*)d_in[7];
    const float* W_fc  = (const float*)d_in[8];   // [OUT,H+OUT]
    const float* b_fc  = (const float*)d_in[9];
    const float* dmask = (const float*)d_in[10];  // [B,H]
    float* y = (float*)d_out;

    // Workspace: h_all[chunkT, B, H] fp32 + carried state h,c [2,B,H].
    const size_t state_bytes = 2ull * BB * HH * sizeof(float);
    const size_t per_t = (size_t)BB * HH * sizeof(float);
    size_t avail = (ws_size > state_bytes) ? (ws_size - state_bytes) : 0;
    int chunkT = (int)(avail / per_t);
    if (chunkT > TT) chunkT = TT;
    if (chunkT < 1) chunkT = 1;

    float* h_all = (float*)d_ws;
    float* state = (float*)((char*)d_ws + (size_t)chunkT * per_t);

    int first = 1;
    for (int t0 = 0; t0 < TT; t0 += chunkT) {
        int tc = TT - t0;
        if (tc > chunkT) tc = chunkT;
        lstm_seq<<<BB, 256, 0, stream>>>(x, W_ih, W_hh, b_ih, b_hh,
                                         h_all, state, t0, tc, first);
        bn_pool_fc<<<tc, 256, 0, stream>>>(h_all, gamma, beta, dmask, pg,
                                           W_fc, b_fc, y, t0, tc);
        first = 0;
    }
}